// Round 9
// baseline (272.948 us; speedup 1.0000x reference)
//
#include <hip/hip_runtime.h>
#include <hip/hip_bf16.h>

typedef unsigned short u16;
typedef __attribute__((ext_vector_type(8))) __bf16 bf16x8;
typedef __attribute__((ext_vector_type(4))) float f32x4;

#define DEV static __device__ __forceinline__

DEV u16 f2bf(float f) {
  union { float f; unsigned u; } c; c.f = f;
  unsigned r = c.u + 0x7fffu + ((c.u >> 16) & 1u);
  return (u16)(r >> 16);
}
DEV float fsig(float x) { return 1.f / (1.f + __expf(-x)); }

DEV void gload_lds16(const void* g, void* l) {
  __builtin_amdgcn_global_load_lds(
      (const __attribute__((address_space(1))) void*)g,
      (__attribute__((address_space(3))) void*)l, 16, 0, 0);
}

// fp32 -> bf16 elementwise (RNE), float4-vectorized
__global__ void cvt_bf16(const float4* __restrict__ src, u16* __restrict__ dst, int n4) {
  int i = blockIdx.x * blockDim.x + threadIdx.x;
  int stride = gridDim.x * blockDim.x;
  for (; i < n4; i += stride) {
    float4 v = src[i];
    union { u16 s[4]; unsigned long long q; } o;
    o.s[0] = f2bf(v.x); o.s[1] = f2bf(v.y); o.s[2] = f2bf(v.z); o.s[3] = f2bf(v.w);
    *(unsigned long long*)&dst[(size_t)i * 4] = o.q;
  }
}

__global__ void cvt_w3(const float4* __restrict__ s0, const float4* __restrict__ s1,
                       const float4* __restrict__ s2, u16* __restrict__ dst, int n4) {
  const float4* src = blockIdx.z == 0 ? s0 : (blockIdx.z == 1 ? s1 : s2);
  u16* d = dst + (size_t)blockIdx.z * n4 * 4;
  int i = blockIdx.x * blockDim.x + threadIdx.x;
  int stride = gridDim.x * blockDim.x;
  for (; i < n4; i += stride) {
    float4 v = src[i];
    union { u16 s[4]; unsigned long long q; } o;
    o.s[0] = f2bf(v.x); o.s[1] = f2bf(v.y); o.s[2] = f2bf(v.z); o.s[3] = f2bf(v.w);
    *(unsigned long long*)&d[(size_t)i * 4] = o.q;
  }
}

// 64x64-tile bf16 transpose: VT[d][k] = V[k][d], per batch (blockIdx.z)
__global__ __launch_bounds__(256) void transpose_bf16(
    const u16* __restrict__ V, u16* __restrict__ VT, int rows, int cols) {
  __shared__ u16 t[64][80];
  const u16* Vb = V + (size_t)blockIdx.z * rows * cols;
  u16* VTb = VT + (size_t)blockIdx.z * rows * cols;
  const int kb = blockIdx.x * 64, db = blockIdx.y * 64;
  const int tid = threadIdx.x;
  const int r = tid >> 3, c8 = (tid & 7) * 8;
#pragma unroll
  for (int it = 0; it < 2; it++) {
    int rr = r + it * 32;
    *(uint4*)&t[rr][c8] = *(const uint4*)&Vb[(size_t)(kb + rr) * cols + db + c8];
  }
  __syncthreads();
#pragma unroll
  for (int it = 0; it < 2; it++) {
    int d = (tid >> 3) + it * 32;
    int k0 = (tid & 7) * 8;
    union { u16 s[8]; uint4 q; } o;
#pragma unroll
    for (int j = 0; j < 8; j++) o.s[j] = t[k0 + j][d];
    *(uint4*)&VTb[(size_t)(db + d) * rows + kb + k0] = o.q;
  }
}

// =============== shared 256^2 8-phase machinery (macros) ===============
#define STAGE(bf, ab, hf, kt_) do {                                         \
    const u16* gp_ = (ab) ? Bt : A;                                         \
    const int rb_ = ((ab) ? brow0 : arow0) + (hf) * 128;                    \
    _Pragma("unroll")                                                       \
    for (int ii_ = 0; ii_ < 2; ii_++) {                                     \
      const int row_ = srow + ii_ * 64;                                     \
      const int c8_ = sslot ^ (row_ & 7);                                   \
      gload_lds16(gp_ + (size_t)(rb_ + row_) * DK + (kt_) + c8_ * 8,        \
                  &lds[bf][ab][hf][wid * 512 + ii_ * 4096]);                \
    }                                                                       \
  } while (0)
#define LDA_(bf, i_, kk_)                                                   \
  (*(const bf16x8*)&lds[bf][0][wr][((i_) * 16 + fr) * 64 +                  \
      ((((kk_) * 4 + kq) ^ (((i_) * 16 + fr) & 7)) * 8)])
#define LDB_(bf, j_, kk_)                                                   \
  (*(const bf16x8*)&lds[bf][1][wc >> 1][((wc & 1) * 64 + (j_) * 16 + fr) * 64 + \
      ((((kk_) * 4 + kq) ^ (((wc & 1) * 64 + (j_) * 16 + fr) & 7)) * 8)])
#define DSA(bf, ih) do {                                                    \
    _Pragma("unroll") for (int i_ = 0; i_ < 4; i_++)                        \
    _Pragma("unroll") for (int k_ = 0; k_ < 2; k_++)                        \
      a_[i_][k_] = LDA_(bf, (ih) + i_, k_);                                 \
  } while (0)
#define DSB(bf, jp) do {                                                    \
    _Pragma("unroll") for (int j_ = 0; j_ < 2; j_++)                        \
    _Pragma("unroll") for (int k_ = 0; k_ < 2; k_++)                        \
      b_[(jp) + j_][k_] = LDB_(bf, (jp) + j_, k_);                          \
  } while (0)
#define MF(ih, jp) do {                                                     \
    _Pragma("unroll") for (int i_ = 0; i_ < 4; i_++)                        \
    _Pragma("unroll") for (int j_ = 0; j_ < 2; j_++)                        \
    _Pragma("unroll") for (int k_ = 0; k_ < 2; k_++)                        \
      acc[(ih) + i_][(jp) + j_] = __builtin_amdgcn_mfma_f32_16x16x32_bf16(  \
          a_[i_][k_], b_[(jp) + j_][k_], acc[(ih) + i_][(jp) + j_], 0, 0, 0); \
  } while (0)
#define BAR() __builtin_amdgcn_s_barrier()
#define LGKM0() asm volatile("s_waitcnt lgkmcnt(0)" ::: "memory")
#define VMC4() asm volatile("s_waitcnt vmcnt(4)" ::: "memory")
#define VMC2() asm volatile("s_waitcnt vmcnt(2)" ::: "memory")
#define PRIO1() __builtin_amdgcn_s_setprio(1)
#define PRIO0() __builtin_amdgcn_s_setprio(0)

// ---------- scores: 256^2, 8-wave, 8-phase (round-6 form, no peel) ----------
// P = sigmoid(sigmoid(Q*K^T)*mask), Q pre-scaled by 1/32. z = batch.
__global__ __launch_bounds__(512, 2) void scores256(
    const u16* __restrict__ Qg, const u16* __restrict__ Kg,
    u16* __restrict__ Pg, const float* __restrict__ maskg) {
  constexpr int S = 4096, DK = 1024;
  __shared__ __align__(16) u16 lds[2][2][2][128 * 64];  // 128 KiB

  const int orig = blockIdx.x + (blockIdx.y << 4);
  const int logical = (orig & 7) * 32 + (orig >> 3);  // 256%8==0: bijective
  const int bm = logical >> 4, bn = logical & 15;
  const int z = blockIdx.z;

  const u16* A = Qg + (size_t)z * S * DK;
  const u16* Bt = Kg + (size_t)z * S * DK;
  const float* mask = maskg + (size_t)z * S * S;
  u16* Cb = Pg + (size_t)z * S * S;

  const int tid = threadIdx.x;
  const int wid = tid >> 6, lane = tid & 63;
  const int wr = wid >> 2, wc = wid & 3;
  const int fr = lane & 15, kq = lane >> 4;
  const int srow = (wid << 3) + (lane >> 3);
  const int sslot = lane & 7;
  const int arow0 = bm * 256, brow0 = bn * 256;

  f32x4 acc[8][4];
#pragma unroll
  for (int i = 0; i < 8; i++)
#pragma unroll
    for (int j = 0; j < 4; j++) acc[i][j] = (f32x4)(0.f);
  bf16x8 a_[4][2], b_[4][2];

  // prologue: tile0 A+B, tile1 B; drain to 4 (tile1-B stays in flight)
  STAGE(0, 0, 0, 0); STAGE(0, 0, 1, 0); STAGE(0, 1, 0, 0); STAGE(0, 1, 1, 0);
  STAGE(1, 1, 0, 64); STAGE(1, 1, 1, 64);
  VMC4();
  BAR();

  constexpr int NIT = DK / 128;  // 8 iterations, 2 K-tiles each
#pragma unroll 1
  for (int t = 0; t < NIT; t++) {
    const int ktv = t * 128 + 64;
    const int kt2 = (t * 128 + 128 < DK) ? t * 128 + 128 : DK - 64;  // clamp tail
    const int kt3 = (t * 128 + 192 < DK) ? t * 128 + 192 : DK - 64;

    DSA(0, 0); DSB(0, 0); STAGE(1, 0, 0, ktv);
    BAR(); LGKM0(); PRIO1(); MF(0, 0); PRIO0(); BAR();
    DSB(0, 2); STAGE(1, 0, 1, ktv);
    BAR(); LGKM0(); PRIO1(); MF(0, 2); PRIO0(); BAR();
    DSA(0, 4); STAGE(0, 1, 0, kt2);
    BAR(); LGKM0(); PRIO1(); MF(4, 2); PRIO0(); BAR();
    STAGE(0, 1, 1, kt2);
    BAR(); LGKM0(); PRIO1(); MF(4, 0); PRIO0(); VMC4(); BAR();
    DSA(1, 0); DSB(1, 0); STAGE(0, 0, 0, kt2);
    BAR(); LGKM0(); PRIO1(); MF(0, 0); PRIO0(); BAR();
    DSB(1, 2); STAGE(0, 0, 1, kt2);
    BAR(); LGKM0(); PRIO1(); MF(0, 2); PRIO0(); BAR();
    DSA(1, 4); STAGE(1, 1, 0, kt3);
    BAR(); LGKM0(); PRIO1(); MF(4, 2); PRIO0(); BAR();
    STAGE(1, 1, 1, kt3);
    BAR(); LGKM0(); PRIO1(); MF(4, 0); PRIO0(); VMC4(); BAR();
  }

  // ---- epilogue boundary: full fence + barrier ----
  asm volatile("s_waitcnt vmcnt(0)" ::: "memory");
  __syncthreads();
  __builtin_amdgcn_sched_barrier(0);

  float* wlds = (float*)lds + wid * 4096;  // 64x64 f32 per wave
  const int rr = lane >> 4, cc = lane & 15;
  const int rbase = bm * 256 + wr * 128;
  const int cbase = bn * 256 + wc * 64;

#define EPIPASS(p_) do {                                                    \
    _Pragma("unroll") for (int ii = 0; ii < 4; ii++)                        \
    _Pragma("unroll") for (int j = 0; j < 4; j++)                           \
    _Pragma("unroll") for (int r = 0; r < 4; r++) {                         \
      const int row = ii * 16 + kq * 4 + r;                                 \
      const int col = (j * 16 + fr) ^ ((row & 7) << 2);                     \
      wlds[row * 64 + col] = acc[(p_) * 4 + ii][j][r];                      \
    }                                                                       \
    _Pragma("unroll") for (int rg = 0; rg < 16; rg++) {                     \
      const int row = rg * 4 + rr;                                          \
      const int colp = (cc * 4) ^ ((row & 7) << 2);                         \
      f32x4 s = *(f32x4*)&wlds[row * 64 + colp];                            \
      const int grow = rbase + (p_) * 64 + row;                             \
      const int gcol = cbase + cc * 4;                                      \
      const float4 m = *(const float4*)&mask[(size_t)grow * S + gcol];      \
      union { u16 h[4]; unsigned long long q; } o;                          \
      o.h[0] = f2bf(fsig(fsig(s[0]) * m.x));                                \
      o.h[1] = f2bf(fsig(fsig(s[1]) * m.y));                                \
      o.h[2] = f2bf(fsig(fsig(s[2]) * m.z));                                \
      o.h[3] = f2bf(fsig(fsig(s[3]) * m.w));                                \
      *(unsigned long long*)&Cb[(size_t)grow * S + gcol] = o.q;             \
    }                                                                       \
  } while (0)

  EPIPASS(0);
  __builtin_amdgcn_sched_barrier(0);
  EPIPASS(1);
#undef EPIPASS
}

// ---------- QKV projection: 256^2, 8-wave, 8-phase ----------
__global__ __launch_bounds__(512, 2) void proj256(
    const u16* __restrict__ hbf, const u16* __restrict__ Wb,
    u16* __restrict__ Cb,
    const float* __restrict__ bias0, const float* __restrict__ bias1,
    const float* __restrict__ bias2) {
  constexpr int M = 8192, N = 1024, DK = 1024;
  __shared__ __align__(16) u16 lds[2][2][2][128 * 64];  // 128 KiB

  const int z = blockIdx.z;
  const int orig = blockIdx.x + (blockIdx.y << 5);     // 128 tiles/z
  const int logical = (orig & 7) * 16 + (orig >> 3);   // bijective XCD chunking
  const int bm = logical >> 2, bn = logical & 3;

  const u16* A = hbf;
  const u16* Bt = Wb + (size_t)z * N * DK;
  const float* bias = z == 0 ? bias0 : (z == 1 ? bias1 : bias2);
  const float scale = z == 0 ? 0.03125f : 1.0f;
  u16* C = Cb + (size_t)z * M * N;

  const int tid = threadIdx.x;
  const int wid = tid >> 6, lane = tid & 63;
  const int wr = wid >> 2, wc = wid & 3;
  const int fr = lane & 15, kq = lane >> 4;
  const int srow = (wid << 3) + (lane >> 3);
  const int sslot = lane & 7;
  const int arow0 = bm * 256, brow0 = bn * 256;

  f32x4 acc[8][4];
#pragma unroll
  for (int i = 0; i < 8; i++)
#pragma unroll
    for (int j = 0; j < 4; j++) acc[i][j] = (f32x4)(0.f);
  bf16x8 a_[4][2], b_[4][2];

  STAGE(0, 0, 0, 0); STAGE(0, 0, 1, 0); STAGE(0, 1, 0, 0); STAGE(0, 1, 1, 0);
  STAGE(1, 1, 0, 64); STAGE(1, 1, 1, 64);
  VMC4();
  BAR();

  constexpr int NIT = DK / 128;
#pragma unroll 1
  for (int t = 0; t < NIT; t++) {
    const int ktv = t * 128 + 64;
    const int kt2 = (t * 128 + 128 < DK) ? t * 128 + 128 : DK - 64;  // clamp tail
    const int kt3 = (t * 128 + 192 < DK) ? t * 128 + 192 : DK - 64;

    DSA(0, 0); DSB(0, 0); STAGE(1, 0, 0, ktv);
    BAR(); LGKM0(); PRIO1(); MF(0, 0); PRIO0(); BAR();
    DSB(0, 2); STAGE(1, 0, 1, ktv);
    BAR(); LGKM0(); PRIO1(); MF(0, 2); PRIO0(); BAR();
    DSA(0, 4); STAGE(0, 1, 0, kt2);
    BAR(); LGKM0(); PRIO1(); MF(4, 2); PRIO0(); BAR();
    STAGE(0, 1, 1, kt2);
    BAR(); LGKM0(); PRIO1(); MF(4, 0); PRIO0(); VMC4(); BAR();
    DSA(1, 0); DSB(1, 0); STAGE(0, 0, 0, kt2);
    BAR(); LGKM0(); PRIO1(); MF(0, 0); PRIO0(); BAR();
    DSB(1, 2); STAGE(0, 0, 1, kt2);
    BAR(); LGKM0(); PRIO1(); MF(0, 2); PRIO0(); BAR();
    DSA(1, 4); STAGE(1, 1, 0, kt3);
    BAR(); LGKM0(); PRIO1(); MF(4, 2); PRIO0(); BAR();
    STAGE(1, 1, 1, kt3);
    BAR(); LGKM0(); PRIO1(); MF(4, 0); PRIO0(); VMC4(); BAR();
  }

  asm volatile("s_waitcnt vmcnt(0)" ::: "memory");
  __syncthreads();
  __builtin_amdgcn_sched_barrier(0);

  float* wlds = (float*)lds + wid * 4096;
  const int rr = lane >> 4, cc = lane & 15;
  const int rbase = bm * 256 + wr * 128;
  const int cbase = bn * 256 + wc * 64;
  const float4 bsv = *(const float4*)&bias[cbase + cc * 4];

#define EPIPASSP(p_) do {                                                   \
    _Pragma("unroll") for (int ii = 0; ii < 4; ii++)                        \
    _Pragma("unroll") for (int j = 0; j < 4; j++)                           \
    _Pragma("unroll") for (int r = 0; r < 4; r++) {                         \
      const int row = ii * 16 + kq * 4 + r;                                 \
      const int col = (j * 16 + fr) ^ ((row & 7) << 2);                     \
      wlds[row * 64 + col] = acc[(p_) * 4 + ii][j][r];                      \
    }                                                                       \
    _Pragma("unroll") for (int rg = 0; rg < 16; rg++) {                     \
      const int row = rg * 4 + rr;                                          \
      const int colp = (cc * 4) ^ ((row & 7) << 2);                         \
      f32x4 s = *(f32x4*)&wlds[row * 64 + colp];                            \
      const int grow = rbase + (p_) * 64 + row;                             \
      const int gcol = cbase + cc * 4;                                      \
      union { u16 h[4]; unsigned long long q; } o;                          \
      o.h[0] = f2bf((s[0] + bsv.x) * scale);                                \
      o.h[1] = f2bf((s[1] + bsv.y) * scale);                                \
      o.h[2] = f2bf((s[2] + bsv.z) * scale);                                \
      o.h[3] = f2bf((s[3] + bsv.w) * scale);                                \
      *(unsigned long long*)&C[(size_t)grow * N + gcol] = o.q;              \
    }                                                                       \
  } while (0)

  EPIPASSP(0);
  __builtin_amdgcn_sched_barrier(0);
  EPIPASSP(1);
#undef EPIPASSP
}

// ---------- PV: 256x128-tile, BK=64, 8-wave (wave tile 128x32), 4-phase/pair ----------
// O[S][D] = P[S][S] * VT[D][S]^T, fp32 out. z = batch. Grid (16,8,2) = 256 blocks.
#define PSTA(bf, hf, kt_) do {                                              \
    _Pragma("unroll")                                                       \
    for (int ii_ = 0; ii_ < 2; ii_++) {                                     \
      const int row_ = srow + ii_ * 64;                                     \
      const int c8_ = sslot ^ (row_ & 7);                                   \
      gload_lds16(A + (size_t)(arow0 + (hf) * 128 + row_) * DK + (kt_) + c8_ * 8, \
                  &ldsa[bf][hf][wid * 512 + ii_ * 4096]);                   \
    }                                                                       \
  } while (0)
#define PSTB(bf, kt_) do {                                                  \
    _Pragma("unroll")                                                       \
    for (int ii_ = 0; ii_ < 2; ii_++) {                                     \
      const int row_ = srow + ii_ * 64;                                     \
      const int c8_ = sslot ^ (row_ & 7);                                   \
      gload_lds16(Bt + (size_t)(brow0 + row_) * DK + (kt_) + c8_ * 8,       \
                  &ldsb[bf][wid * 512 + ii_ * 4096]);                       \
    }                                                                       \
  } while (0)
#define PDSA(bf, ih) do {                                                   \
    _Pragma("unroll") for (int i_ = 0; i_ < 4; i_++)                        \
    _Pragma("unroll") for (int k_ = 0; k_ < 2; k_++)                        \
      a_[i_][k_] = *(const bf16x8*)&ldsa[bf][wr][(((ih) + i_) * 16 + fr) * 64 + \
          (((k_ * 4 + kq) ^ ((((ih) + i_) * 16 + fr) & 7)) * 8)];           \
  } while (0)
#define PDSB(bf) do {                                                       \
    _Pragma("unroll") for (int j_ = 0; j_ < 2; j_++)                        \
    _Pragma("unroll") for (int k_ = 0; k_ < 2; k_++)                        \
      b_[j_][k_] = *(const bf16x8*)&ldsb[bf][(wc * 32 + j_ * 16 + fr) * 64 + \
          (((k_ * 4 + kq) ^ ((wc * 32 + j_ * 16 + fr) & 7)) * 8)];          \
  } while (0)
#define PMF(ih) do {                                                        \
    _Pragma("unroll") for (int i_ = 0; i_ < 4; i_++)                        \
    _Pragma("unroll") for (int j_ = 0; j_ < 2; j_++)                        \
    _Pragma("unroll") for (int k_ = 0; k_ < 2; k_++)                        \
      acc[(ih) + i_][j_] = __builtin_amdgcn_mfma_f32_16x16x32_bf16(         \
          a_[i_][k_], b_[j_][k_], acc[(ih) + i_][j_], 0, 0, 0);             \
  } while (0)

__global__ __launch_bounds__(512, 2) void pv256(
    const u16* __restrict__ Pg, const u16* __restrict__ VTg,
    float* __restrict__ Og) {
  constexpr int S = 4096, DN = 1024, DK = 4096;
  __shared__ __align__(16) u16 ldsa[2][2][128 * 64];  // 64 KiB
  __shared__ __align__(16) u16 ldsb[2][128 * 64];     // 32 KiB

  const int z = blockIdx.z;
  const int orig = blockIdx.x + (blockIdx.y << 4);    // 128 tiles/plane
  const int logical = (orig & 7) * 16 + (orig >> 3);  // bijective (128%8==0)
  const int bm = logical >> 3, bn = logical & 7;      // same-bm chunked: P-panel reuse

  const u16* A = Pg + (size_t)z * S * S;
  const u16* Bt = VTg + (size_t)z * DN * S;
  float* C = Og + (size_t)z * S * DN;

  const int tid = threadIdx.x;
  const int wid = tid >> 6, lane = tid & 63;
  const int wr = wid >> 2, wc = wid & 3;   // wave tile 128 x 32
  const int fr = lane & 15, kq = lane >> 4;
  const int srow = (wid << 3) + (lane >> 3);
  const int sslot = lane & 7;
  const int arow0 = bm * 256, brow0 = bn * 128;

  f32x4 acc[8][2];
#pragma unroll
  for (int i = 0; i < 8; i++)
#pragma unroll
    for (int j = 0; j < 2; j++) acc[i][j] = (f32x4)(0.f);
  bf16x8 a_[4][2], b_[2][2];

  // prologue: A(0) both halves + B(0); B(1). 8 loads; drain to 2 (B(1) in flight)
  PSTA(0, 0, 0); PSTA(0, 1, 0); PSTB(0, 0);
  PSTB(1, 64);
  VMC2();
  BAR();

  constexpr int NP = DK / 128;  // 32 pair-iterations
#pragma unroll 1
  for (int t = 0; t < NP; t++) {
    const int ktv = t * 128 + 64;
    const int ku2 = (t * 128 + 128 < DK) ? t * 128 + 128 : DK - 64;  // clamp tail
    const int kv2 = (t * 128 + 192 < DK) ? t * 128 + 192 : DK - 64;

    // P1: compute u rows 0-63 (per wave-half); stage A0(v)
    PDSA(0, 0); PDSB(0); PSTA(1, 0, ktv);
    BAR(); LGKM0(); PRIO1(); PMF(0); PRIO0(); BAR();
    // P2: u rows 64-127; stage A1(v) + B(u+2); drain all of tile v's deps
    PDSA(0, 4); PSTA(1, 1, ktv); PSTB(0, ku2);
    BAR(); LGKM0(); PRIO1(); PMF(4); PRIO0(); VMC2(); BAR();
    // P3: tile v; stage A0(u+2)
    PDSA(1, 0); PDSB(1); PSTA(0, 0, ku2);
    BAR(); LGKM0(); PRIO1(); PMF(0); PRIO0(); BAR();
    // P4: stage A1(u+2) + B(v+2); drain tile u+2's deps
    PDSA(1, 4); PSTA(0, 1, ku2); PSTB(1, kv2);
    BAR(); LGKM0(); PRIO1(); PMF(4); PRIO0(); VMC2(); BAR();
  }

  asm volatile("s_waitcnt vmcnt(0)" ::: "memory");

  // epilogue: direct fp32 stores (16 consecutive cols per (j,kq) group)
  const int rbase = bm * 256 + wr * 128;
  const int cbase = bn * 128 + wc * 32;
#pragma unroll
  for (int i = 0; i < 8; i++)
#pragma unroll
    for (int j = 0; j < 2; j++) {
      const int col = cbase + j * 16 + fr;
#pragma unroll
      for (int r = 0; r < 4; r++) {
        const int row = rbase + i * 16 + kq * 4 + r;
        C[(size_t)row * DN + col] = acc[i][j][r];
      }
    }
}

extern "C" void kernel_launch(void* const* d_in, const int* in_sizes, int n_in,
                              void* d_out, int out_size, void* d_ws, size_t ws_size,
                              hipStream_t stream) {
  const int B = 2, S = 4096, D = 1024;
  const float* hid  = (const float*)d_in[0];
  const float* mask = (const float*)d_in[1];
  const float* Wq = (const float*)d_in[2];
  const float* bq = (const float*)d_in[3];
  const float* Wk = (const float*)d_in[4];
  const float* bk = (const float*)d_in[5];
  const float* Wv = (const float*)d_in[6];
  const float* bv = (const float*)d_in[7];

  const size_t MT = (size_t)B * S * D;  // 8388608
  u16* hbf = (u16*)d_ws;                // MT
  u16* wbf = hbf + MT;                  // 3*D*D
  u16* Qb  = wbf + 3 * (size_t)D * D;   // MT (Q,K,V contiguous)
  u16* Kb  = Qb + MT;
  u16* Vb  = Kb + MT;
  u16* VTb = Vb + MT;                   // MT
  u16* Pb  = VTb + MT;                  // B*S*S

  // 1. converts
  cvt_bf16<<<2048, 256, 0, stream>>>((const float4*)hid, hbf, (int)(MT / 4));
  cvt_w3<<<dim3(512, 1, 3), 256, 0, stream>>>(
      (const float4*)Wq, (const float4*)Wk, (const float4*)Wv, wbf, D * D / 4);

  // 2. fused QKV projection (256^2 8-phase)
  proj256<<<dim3(32, 4, 3), 512, 0, stream>>>(hbf, wbf, Qb, bq, bk, bv);

  // 3. V transpose per batch
  transpose_bf16<<<dim3(S / 64, D / 64, B), 256, 0, stream>>>(Vb, VTb, S, D);

  // 4. scores (round-6 8-phase), both batches
  scores256<<<dim3(S / 256, S / 256, B), 512, 0, stream>>>(Qb, Kb, Pb, mask);

  // 5. P*V (256x128 8-phase)
  pv256<<<dim3(S / 256, D / 128, B), 512, 0, stream>>>(Pb, VTb, (float*)d_out);
}

// Round 10
// 256.274 us; speedup vs baseline: 1.0651x; 1.0651x over previous
//
#include <hip/hip_runtime.h>
#include <hip/hip_bf16.h>

typedef unsigned short u16;
typedef __attribute__((ext_vector_type(8))) __bf16 bf16x8;
typedef __attribute__((ext_vector_type(4))) float f32x4;

#define DEV static __device__ __forceinline__

DEV u16 f2bf(float f) {
  union { float f; unsigned u; } c; c.f = f;
  unsigned r = c.u + 0x7fffu + ((c.u >> 16) & 1u);
  return (u16)(r >> 16);
}
DEV float fsig(float x) { return 1.f / (1.f + __expf(-x)); }

DEV void gload_lds16(const void* g, void* l) {
  __builtin_amdgcn_global_load_lds(
      (const __attribute__((address_space(1))) void*)g,
      (__attribute__((address_space(3))) void*)l, 16, 0, 0);
}

// fp32 -> bf16 elementwise (RNE), float4-vectorized
__global__ void cvt_bf16(const float4* __restrict__ src, u16* __restrict__ dst, int n4) {
  int i = blockIdx.x * blockDim.x + threadIdx.x;
  int stride = gridDim.x * blockDim.x;
  for (; i < n4; i += stride) {
    float4 v = src[i];
    union { u16 s[4]; unsigned long long q; } o;
    o.s[0] = f2bf(v.x); o.s[1] = f2bf(v.y); o.s[2] = f2bf(v.z); o.s[3] = f2bf(v.w);
    *(unsigned long long*)&dst[(size_t)i * 4] = o.q;
  }
}

__global__ void cvt_w3(const float4* __restrict__ s0, const float4* __restrict__ s1,
                       const float4* __restrict__ s2, u16* __restrict__ dst, int n4) {
  const float4* src = blockIdx.z == 0 ? s0 : (blockIdx.z == 1 ? s1 : s2);
  u16* d = dst + (size_t)blockIdx.z * n4 * 4;
  int i = blockIdx.x * blockDim.x + threadIdx.x;
  int stride = gridDim.x * blockDim.x;
  for (; i < n4; i += stride) {
    float4 v = src[i];
    union { u16 s[4]; unsigned long long q; } o;
    o.s[0] = f2bf(v.x); o.s[1] = f2bf(v.y); o.s[2] = f2bf(v.z); o.s[3] = f2bf(v.w);
    *(unsigned long long*)&d[(size_t)i * 4] = o.q;
  }
}

// 64x64-tile bf16 transpose: VT[d][k] = V[k][d], per batch (blockIdx.z)
__global__ __launch_bounds__(256) void transpose_bf16(
    const u16* __restrict__ V, u16* __restrict__ VT, int rows, int cols) {
  __shared__ u16 t[64][80];
  const u16* Vb = V + (size_t)blockIdx.z * rows * cols;
  u16* VTb = VT + (size_t)blockIdx.z * rows * cols;
  const int kb = blockIdx.x * 64, db = blockIdx.y * 64;
  const int tid = threadIdx.x;
  const int r = tid >> 3, c8 = (tid & 7) * 8;
#pragma unroll
  for (int it = 0; it < 2; it++) {
    int rr = r + it * 32;
    *(uint4*)&t[rr][c8] = *(const uint4*)&Vb[(size_t)(kb + rr) * cols + db + c8];
  }
  __syncthreads();
#pragma unroll
  for (int it = 0; it < 2; it++) {
    int d = (tid >> 3) + it * 32;
    int k0 = (tid & 7) * 8;
    union { u16 s[8]; uint4 q; } o;
#pragma unroll
    for (int j = 0; j < 8; j++) o.s[j] = t[k0 + j][d];
    *(uint4*)&VTb[(size_t)(db + d) * rows + kb + k0] = o.q;
  }
}

// ---------- 128^2 m97-structure GEMM (QKV and PV) ----------
template <int EPI>
__global__ __launch_bounds__(256, 2) void gemm_bt(
    const u16* __restrict__ A, const u16* __restrict__ Bt,
    u16* __restrict__ Cb, float* __restrict__ Cf,
    const float* __restrict__ bias0, const float* __restrict__ bias1,
    const float* __restrict__ bias2,
    int M, int N, int K) {
  __shared__ __align__(16) u16 As[128 * 64];
  __shared__ __align__(16) u16 Bs[128 * 64];

  const int bm = blockIdx.x, bn = blockIdx.y, z = blockIdx.z;
  if (EPI == 0) {
    Bt += (size_t)z * N * K;
  } else {
    A += (size_t)z * M * K;
    Bt += (size_t)z * N * K;
  }
  const size_t cofs = (size_t)z * M * N;
  const float* bias = (EPI == 0) ? (z == 0 ? bias0 : (z == 1 ? bias1 : bias2)) : nullptr;
  const float scale = (EPI == 0 && z == 0) ? 0.03125f : 1.0f;

  const int tid = threadIdx.x;
  const int wid = tid >> 6, lane = tid & 63;
  const int wr = wid >> 1, wc = wid & 1;
  const int l3 = lane >> 3, sl = lane & 7;
  const int srcslot = sl ^ l3;

  const u16* Ag = A + (size_t)(bm * 128 + wid * 32 + l3) * K + srcslot * 8;
  const u16* Bg = Bt + (size_t)(bn * 128 + wid * 32 + l3) * K + srcslot * 8;
  u16* AsW = &As[wid * 32 * 64];
  u16* BsW = &Bs[wid * 32 * 64];

  f32x4 acc[4][4];
#pragma unroll
  for (int i = 0; i < 4; i++)
#pragma unroll
    for (int j = 0; j < 4; j++) acc[i][j] = (f32x4)(0.f);

  const int fr = lane & 15, kq = lane >> 4;

  for (int kt = 0; kt < K; kt += 64) {
#pragma unroll
    for (int i = 0; i < 4; i++) {
      gload_lds16(Ag + kt + i * 8 * K, AsW + i * 8 * 64);
      gload_lds16(Bg + kt + i * 8 * K, BsW + i * 8 * 64);
    }
    __syncthreads();
#pragma unroll
    for (int ks = 0; ks < 2; ks++) {
      bf16x8 af[4], bfr[4];
#pragma unroll
      for (int i = 0; i < 4; i++) {
        const int ra = wr * 64 + i * 16 + fr;
        af[i] = *(const bf16x8*)&As[ra * 64 + (((ks * 4 + kq) ^ (ra & 7)) * 8)];
        const int rb = wc * 64 + i * 16 + fr;
        bfr[i] = *(const bf16x8*)&Bs[rb * 64 + (((ks * 4 + kq) ^ (rb & 7)) * 8)];
      }
#pragma unroll
      for (int i = 0; i < 4; i++)
#pragma unroll
        for (int j = 0; j < 4; j++)
          acc[i][j] = __builtin_amdgcn_mfma_f32_16x16x32_bf16(af[i], bfr[j], acc[i][j], 0, 0, 0);
    }
    __syncthreads();
  }

  const int rbase = bm * 128 + wr * 64;
  const int cbase = bn * 128 + wc * 64;
#pragma unroll
  for (int i = 0; i < 4; i++)
#pragma unroll
    for (int j = 0; j < 4; j++) {
      const int col = cbase + j * 16 + fr;
#pragma unroll
      for (int r = 0; r < 4; r++) {
        const int row = rbase + i * 16 + kq * 4 + r;
        float v = acc[i][j][r];
        if (EPI == 0) {
          v = (v + bias[col]) * scale;
          Cb[cofs + (size_t)row * N + col] = f2bf(v);
        } else {
          Cf[cofs + (size_t)row * N + col] = v;
        }
      }
    }
}

// ---------- scores: 256x256-tile, BK=64, 8-wave, 8-phase counted-vmcnt ----------
// P = sigmoid(sigmoid(Q*K^T)*mask), Q pre-scaled by 1/32. z = batch.
// Epilogue: per-wave LDS transpose (static indices) -> float4 mask + packed bf16.
// Boundary to epilogue uses __syncthreads(): raw s_barrier is NOT a compiler
// memory fence, and other waves' tail STAGE DMAs land inside this wave's wlds.
__global__ __launch_bounds__(512, 2) void scores256(
    const u16* __restrict__ Qg, const u16* __restrict__ Kg,
    u16* __restrict__ Pg, const float* __restrict__ maskg) {
  constexpr int S = 4096, DK = 1024;
  __shared__ __align__(16) u16 lds[2][2][2][128 * 64];  // 128 KiB

  // T1 bijective XCD swizzle within each batch plane (256 tiles, 256%8==0)
  const int orig = blockIdx.x + (blockIdx.y << 4);
  const int logical = (orig & 7) * 32 + (orig >> 3);
  const int bm = logical >> 4, bn = logical & 15;
  const int z = blockIdx.z;

  const u16* A = Qg + (size_t)z * S * DK;
  const u16* Bt = Kg + (size_t)z * S * DK;
  const float* mask = maskg + (size_t)z * S * S;
  u16* Cb = Pg + (size_t)z * S * S;

  const int tid = threadIdx.x;
  const int wid = tid >> 6, lane = tid & 63;
  const int wr = wid >> 2, wc = wid & 3;      // 2x4 wave grid; wave tile 128x64
  const int fr = lane & 15, kq = lane >> 4;

  const int srow = (wid << 3) + (lane >> 3);  // staging row (+64 per issue)
  const int sslot = lane & 7;
  const int arow0 = bm * 256, brow0 = bn * 256;

  f32x4 acc[8][4];
#pragma unroll
  for (int i = 0; i < 8; i++)
#pragma unroll
    for (int j = 0; j < 4; j++) acc[i][j] = (f32x4)(0.f);
  bf16x8 a_[4][2], b_[4][2];

#define STAGE(bf, ab, hf, kt_) do {                                         \
    const u16* gp_ = (ab) ? Bt : A;                                         \
    const int rb_ = ((ab) ? brow0 : arow0) + (hf) * 128;                    \
    _Pragma("unroll")                                                       \
    for (int ii_ = 0; ii_ < 2; ii_++) {                                     \
      const int row_ = srow + ii_ * 64;                                     \
      const int c8_ = sslot ^ (row_ & 7);                                   \
      gload_lds16(gp_ + (size_t)(rb_ + row_) * DK + (kt_) + c8_ * 8,        \
                  &lds[bf][ab][hf][wid * 512 + ii_ * 4096]);                \
    }                                                                       \
  } while (0)

#define LDA_(bf, i_, kk_)                                                   \
  (*(const bf16x8*)&lds[bf][0][wr][((i_) * 16 + fr) * 64 +                  \
      ((((kk_) * 4 + kq) ^ (((i_) * 16 + fr) & 7)) * 8)])
#define LDB_(bf, j_, kk_)                                                   \
  (*(const bf16x8*)&lds[bf][1][wc >> 1][((wc & 1) * 64 + (j_) * 16 + fr) * 64 + \
      ((((kk_) * 4 + kq) ^ (((wc & 1) * 64 + (j_) * 16 + fr) & 7)) * 8)])

#define DSA(bf, ih) do {                                                    \
    _Pragma("unroll") for (int i_ = 0; i_ < 4; i_++)                        \
    _Pragma("unroll") for (int k_ = 0; k_ < 2; k_++)                        \
      a_[i_][k_] = LDA_(bf, (ih) + i_, k_);                                 \
  } while (0)
#define DSB(bf, jp) do {                                                    \
    _Pragma("unroll") for (int j_ = 0; j_ < 2; j_++)                        \
    _Pragma("unroll") for (int k_ = 0; k_ < 2; k_++)                        \
      b_[(jp) + j_][k_] = LDB_(bf, (jp) + j_, k_);                          \
  } while (0)
#define MF(ih, jp) do {                                                     \
    _Pragma("unroll") for (int i_ = 0; i_ < 4; i_++)                        \
    _Pragma("unroll") for (int j_ = 0; j_ < 2; j_++)                        \
    _Pragma("unroll") for (int k_ = 0; k_ < 2; k_++)                        \
      acc[(ih) + i_][(jp) + j_] = __builtin_amdgcn_mfma_f32_16x16x32_bf16(  \
          a_[i_][k_], b_[(jp) + j_][k_], acc[(ih) + i_][(jp) + j_], 0, 0, 0); \
  } while (0)
#define BAR() __builtin_amdgcn_s_barrier()
#define LGKM0() asm volatile("s_waitcnt lgkmcnt(0)" ::: "memory")
#define VMC4() asm volatile("s_waitcnt vmcnt(4)" ::: "memory")

  // prologue: tile0 full (A0,A1,B0,B1) + tile1 (B0,B1); drain to 4
  STAGE(0, 0, 0, 0); STAGE(0, 0, 1, 0); STAGE(0, 1, 0, 0); STAGE(0, 1, 1, 0);
  STAGE(1, 1, 0, 64); STAGE(1, 1, 1, 64);
  VMC4();
  BAR();

  constexpr int NIT = DK / 128;  // 8 iterations, 2 K-tiles each
#pragma unroll 1
  for (int t = 0; t < NIT; t++) {
    const int ktv = t * 128 + 64;
    const int kt2 = (t * 128 + 128 < DK) ? t * 128 + 128 : DK - 64;  // clamp tail
    const int kt3 = (t * 128 + 192 < DK) ? t * 128 + 192 : DK - 64;

    // --- tile u = 2t (buf0) ---
    DSA(0, 0); DSB(0, 0);
    STAGE(1, 0, 0, ktv);
    BAR(); LGKM0();
    __builtin_amdgcn_s_setprio(1); MF(0, 0); __builtin_amdgcn_s_setprio(0);
    BAR();
    DSB(0, 2);
    STAGE(1, 0, 1, ktv);
    BAR(); LGKM0();
    __builtin_amdgcn_s_setprio(1); MF(0, 2); __builtin_amdgcn_s_setprio(0);
    BAR();
    DSA(0, 4);
    STAGE(0, 1, 0, kt2);
    BAR(); LGKM0();
    __builtin_amdgcn_s_setprio(1); MF(4, 2); __builtin_amdgcn_s_setprio(0);
    BAR();
    STAGE(0, 1, 1, kt2);
    BAR(); LGKM0();
    __builtin_amdgcn_s_setprio(1); MF(4, 0); __builtin_amdgcn_s_setprio(0);
    VMC4();
    BAR();
    // --- tile v = 2t+1 (buf1) ---
    DSA(1, 0); DSB(1, 0);
    STAGE(0, 0, 0, kt2);
    BAR(); LGKM0();
    __builtin_amdgcn_s_setprio(1); MF(0, 0); __builtin_amdgcn_s_setprio(0);
    BAR();
    DSB(1, 2);
    STAGE(0, 0, 1, kt2);
    BAR(); LGKM0();
    __builtin_amdgcn_s_setprio(1); MF(0, 2); __builtin_amdgcn_s_setprio(0);
    BAR();
    DSA(1, 4);
    STAGE(1, 1, 0, kt3);
    BAR(); LGKM0();
    __builtin_amdgcn_s_setprio(1); MF(4, 2); __builtin_amdgcn_s_setprio(0);
    BAR();
    STAGE(1, 1, 1, kt3);
    BAR(); LGKM0();
    __builtin_amdgcn_s_setprio(1); MF(4, 0); __builtin_amdgcn_s_setprio(0);
    VMC4();
    BAR();
  }

  // ---- epilogue boundary: FULL fence + barrier (not raw s_barrier!) ----
  asm volatile("s_waitcnt vmcnt(0)" ::: "memory");
  __syncthreads();  // IR-level memory fence: no LDS op crosses; all waves' DMAs landed
  __builtin_amdgcn_sched_barrier(0);

  float* wlds = (float*)lds + wid * 4096;  // 64x64 f32 per wave (16 KiB)
  const int rr = lane >> 4, cc = lane & 15;
  const int rbase = bm * 256 + wr * 128;
  const int cbase = bn * 256 + wc * 64;

  // p_ MUST be a literal so acc[] indices are compile-time (rule #20).
#define EPIPASS(p_) do {                                                    \
    _Pragma("unroll") for (int ii = 0; ii < 4; ii++)                        \
    _Pragma("unroll") for (int j = 0; j < 4; j++)                           \
    _Pragma("unroll") for (int r = 0; r < 4; r++) {                         \
      const int row = ii * 16 + kq * 4 + r;                                 \
      const int col = (j * 16 + fr) ^ ((row & 7) << 2);                     \
      wlds[row * 64 + col] = acc[(p_) * 4 + ii][j][r];                      \
    }                                                                       \
    _Pragma("unroll 4") for (int rg = 0; rg < 16; rg++) {                   \
      const int row = rg * 4 + rr;                                          \
      const int colp = (cc * 4) ^ ((row & 7) << 2);                         \
      f32x4 s = *(f32x4*)&wlds[row * 64 + colp];                            \
      const int grow = rbase + (p_) * 64 + row;                             \
      const int gcol = cbase + cc * 4;                                      \
      const float4 m = *(const float4*)&mask[(size_t)grow * S + gcol];      \
      union { u16 h[4]; unsigned long long q; } o;                          \
      o.h[0] = f2bf(fsig(fsig(s[0]) * m.x));                                \
      o.h[1] = f2bf(fsig(fsig(s[1]) * m.y));                                \
      o.h[2] = f2bf(fsig(fsig(s[2]) * m.z));                                \
      o.h[3] = f2bf(fsig(fsig(s[3]) * m.w));                                \
      *(unsigned long long*)&Cb[(size_t)grow * S + gcol] = o.q;             \
    }                                                                       \
  } while (0)

  EPIPASS(0);
  __builtin_amdgcn_sched_barrier(0);  // pin pass-0 reads before pass-1 writes
  EPIPASS(1);
#undef EPIPASS
#undef STAGE
#undef LDA_
#undef LDB_
#undef DSA
#undef DSB
#undef MF
#undef BAR
#undef LGKM0
#undef VMC4
}

extern "C" void kernel_launch(void* const* d_in, const int* in_sizes, int n_in,
                              void* d_out, int out_size, void* d_ws, size_t ws_size,
                              hipStream_t stream) {
  const int B = 2, S = 4096, D = 1024;
  const float* hid  = (const float*)d_in[0];
  const float* mask = (const float*)d_in[1];
  const float* Wq = (const float*)d_in[2];
  const float* bq = (const float*)d_in[3];
  const float* Wk = (const float*)d_in[4];
  const float* bk = (const float*)d_in[5];
  const float* Wv = (const float*)d_in[6];
  const float* bv = (const float*)d_in[7];

  const size_t MT = (size_t)B * S * D;  // 8388608
  u16* hbf = (u16*)d_ws;                // MT
  u16* wbf = hbf + MT;                  // 3*D*D
  u16* Qb  = wbf + 3 * (size_t)D * D;   // MT  (Q,K,V contiguous: EPI0 z-offset)
  u16* Kb  = Qb + MT;
  u16* Vb  = Kb + MT;
  u16* VTb = Vb + MT;                   // MT
  u16* Pb  = VTb + MT;                  // B*S*S

  // 1. converts
  cvt_bf16<<<2048, 256, 0, stream>>>((const float4*)hid, hbf, (int)(MT / 4));
  cvt_w3<<<dim3(512, 1, 3), 256, 0, stream>>>(
      (const float4*)Wq, (const float4*)Wk, (const float4*)Wv, wbf, D * D / 4);

  // 2. fused QKV projection
  gemm_bt<0><<<dim3(B * S / 128, D / 128, 3), 256, 0, stream>>>(
      hbf, wbf, Qb, nullptr, bq, bk, bv, B * S, D, D);

  // 3. V transpose per batch
  transpose_bf16<<<dim3(S / 64, D / 64, B), 256, 0, stream>>>(Vb, VTb, S, D);

  // 4. scores (256^2 8-phase + fenced vectorized epilogue), both batches
  scores256<<<dim3(S / 256, S / 256, B), 512, 0, stream>>>(Qb, Kb, Pb, mask);

  // 5. P*V
  gemm_bt<2><<<dim3(S / 128, D / 128, B), 256, 0, stream>>>(
      Pb, VTb, nullptr, (float*)d_out, nullptr, nullptr, nullptr, S, D, S);
}

// Round 11
// 246.595 us; speedup vs baseline: 1.1069x; 1.0393x over previous
//
#include <hip/hip_runtime.h>
#include <hip/hip_bf16.h>

typedef unsigned short u16;
typedef unsigned long long u64;
typedef __attribute__((ext_vector_type(8))) __bf16 bf16x8;
typedef __attribute__((ext_vector_type(4))) float f32x4;

#define DEV static __device__ __forceinline__

DEV u16 f2bf(float f) {
  union { float f; unsigned u; } c; c.f = f;
  unsigned r = c.u + 0x7fffu + ((c.u >> 16) & 1u);
  return (u16)(r >> 16);
}
DEV float fsig(float x) { return 1.f / (1.f + __expf(-x)); }

DEV void gload_lds16(const void* g, void* l) {
  __builtin_amdgcn_global_load_lds(
      (const __attribute__((address_space(1))) void*)g,
      (__attribute__((address_space(3))) void*)l, 16, 0, 0);
}

// fp32 -> bf16 elementwise (RNE), float4-vectorized
__global__ void cvt_bf16(const float4* __restrict__ src, u16* __restrict__ dst, int n4) {
  int i = blockIdx.x * blockDim.x + threadIdx.x;
  int stride = gridDim.x * blockDim.x;
  for (; i < n4; i += stride) {
    float4 v = src[i];
    union { u16 s[4]; u64 q; } o;
    o.s[0] = f2bf(v.x); o.s[1] = f2bf(v.y); o.s[2] = f2bf(v.z); o.s[3] = f2bf(v.w);
    *(u64*)&dst[(size_t)i * 4] = o.q;
  }
}

__global__ void cvt_w3(const float4* __restrict__ s0, const float4* __restrict__ s1,
                       const float4* __restrict__ s2, u16* __restrict__ dst, int n4) {
  const float4* src = blockIdx.z == 0 ? s0 : (blockIdx.z == 1 ? s1 : s2);
  u16* d = dst + (size_t)blockIdx.z * n4 * 4;
  int i = blockIdx.x * blockDim.x + threadIdx.x;
  int stride = gridDim.x * blockDim.x;
  for (; i < n4; i += stride) {
    float4 v = src[i];
    union { u16 s[4]; u64 q; } o;
    o.s[0] = f2bf(v.x); o.s[1] = f2bf(v.y); o.s[2] = f2bf(v.z); o.s[3] = f2bf(v.w);
    *(u64*)&d[(size_t)i * 4] = o.q;
  }
}

// ---------- 128^2 m97-structure GEMM ----------
// EPI 0: QKV projection. z=0: Q (scaled 1/32) -> Cb; z=1: K -> Cb;
//        z=2: V -> written TRANSPOSED to VTb (per batch) via in-LDS transpose.
// EPI 2: PV (z = batch): plain fp32 out to Cf.
template <int EPI>
__global__ __launch_bounds__(256, 2) void gemm_bt(
    const u16* __restrict__ A, const u16* __restrict__ Bt,
    u16* __restrict__ Cb, float* __restrict__ Cf, u16* __restrict__ VTb,
    const float* __restrict__ bias0, const float* __restrict__ bias1,
    const float* __restrict__ bias2,
    int M, int N, int K) {
  __shared__ __align__(16) u16 smem[2 * 128 * 64];  // As | Bs (contiguous)
  u16* As = smem;
  u16* Bs = smem + 128 * 64;

  const int bm = blockIdx.x, bn = blockIdx.y, z = blockIdx.z;
  if (EPI == 0) {
    Bt += (size_t)z * N * K;
  } else {
    A += (size_t)z * M * K;
    Bt += (size_t)z * N * K;
  }
  const size_t cofs = (size_t)z * M * N;
  const float* bias = (EPI == 0) ? (z == 0 ? bias0 : (z == 1 ? bias1 : bias2)) : nullptr;
  const float scale = (EPI == 0 && z == 0) ? 0.03125f : 1.0f;

  const int tid = threadIdx.x;
  const int wid = tid >> 6, lane = tid & 63;
  const int wr = wid >> 1, wc = wid & 1;
  const int l3 = lane >> 3, sl = lane & 7;
  const int srcslot = sl ^ l3;

  const u16* Ag = A + (size_t)(bm * 128 + wid * 32 + l3) * K + srcslot * 8;
  const u16* Bg = Bt + (size_t)(bn * 128 + wid * 32 + l3) * K + srcslot * 8;
  u16* AsW = &As[wid * 32 * 64];
  u16* BsW = &Bs[wid * 32 * 64];

  f32x4 acc[4][4];
#pragma unroll
  for (int i = 0; i < 4; i++)
#pragma unroll
    for (int j = 0; j < 4; j++) acc[i][j] = (f32x4)(0.f);

  const int fr = lane & 15, kq = lane >> 4;

  for (int kt = 0; kt < K; kt += 64) {
#pragma unroll
    for (int i = 0; i < 4; i++) {
      gload_lds16(Ag + kt + i * 8 * K, AsW + i * 8 * 64);
      gload_lds16(Bg + kt + i * 8 * K, BsW + i * 8 * 64);
    }
    __syncthreads();
#pragma unroll
    for (int ks = 0; ks < 2; ks++) {
      bf16x8 af[4], bfr[4];
#pragma unroll
      for (int i = 0; i < 4; i++) {
        const int ra = wr * 64 + i * 16 + fr;
        af[i] = *(const bf16x8*)&As[ra * 64 + (((ks * 4 + kq) ^ (ra & 7)) * 8)];
        const int rb = wc * 64 + i * 16 + fr;
        bfr[i] = *(const bf16x8*)&Bs[rb * 64 + (((ks * 4 + kq) ^ (rb & 7)) * 8)];
      }
#pragma unroll
      for (int i = 0; i < 4; i++)
#pragma unroll
        for (int j = 0; j < 4; j++)
          acc[i][j] = __builtin_amdgcn_mfma_f32_16x16x32_bf16(af[i], bfr[j], acc[i][j], 0, 0, 0);
    }
    __syncthreads();
  }
  // after the final __syncthreads() above, all waves are done reading smem.

  const int rbase = bm * 128 + wr * 64;
  const int cbase = bn * 128 + wc * 64;

  if (EPI == 0 && z == 2) {
    // ---- V: write transposed via per-wave 64x64 bf16 LDS transpose ----
    // Wave-private region: smem[wid*4096 .. +4096). Row dl (64 u16), slot
    // swizzle: physical slot = slot ^ (dl & 15), 4 u16 per slot.
    u16* tl = smem + wid * 4096;
#pragma unroll
    for (int i = 0; i < 4; i++)
#pragma unroll
      for (int j = 0; j < 4; j++) {
        const int dl = j * 16 + fr;          // transposed row (d-local)
        const int slot = i * 4 + kq;         // 4 u16 along s-local
        union { u16 h[4]; u64 q; } o;
#pragma unroll
        for (int r = 0; r < 4; r++) o.h[r] = f2bf(acc[i][j][r] + bias[cbase + dl]);
        *(u64*)&tl[dl * 64 + ((slot ^ (dl & 15)) * 4)] = o.q;
      }
    // same-wave DS ordering guarantees writes complete before reads below.
    const int batch = bm >> 5;               // bm*128 / 4096
    u16* VTw = VTb + (size_t)batch * 4096 * 1024;
    const int d0 = cbase;                    // 64 d-rows of VT
    const int s0 = rbase - batch * 4096;     // 64 s-cols
    const int rl = lane >> 4, sslot2 = lane & 15;
#pragma unroll
    for (int rb = 0; rb < 16; rb++) {
      const int dl = rb * 4 + rl;
      const u64 q = *(const u64*)&tl[dl * 64 + ((sslot2 ^ (dl & 15)) * 4)];
      *(u64*)&VTw[(size_t)(d0 + dl) * 4096 + s0 + sslot2 * 4] = q;
    }
  } else {
#pragma unroll
    for (int i = 0; i < 4; i++)
#pragma unroll
      for (int j = 0; j < 4; j++) {
        const int col = cbase + j * 16 + fr;
#pragma unroll
        for (int r = 0; r < 4; r++) {
          const int row = rbase + i * 16 + kq * 4 + r;
          float v = acc[i][j][r];
          if (EPI == 0) {
            v = (v + bias[col]) * scale;
            Cb[cofs + (size_t)row * N + col] = f2bf(v);
          } else {
            Cf[cofs + (size_t)row * N + col] = v;
          }
        }
      }
  }
}

// ---------- scores: 256x256-tile, BK=64, 8-wave, 8-phase counted-vmcnt ----------
// P = sigmoid(sigmoid(Q*K^T)*mask), Q pre-scaled by 1/32. z = batch.
// Epilogue: per-wave LDS transpose (static indices) -> float4 mask + packed bf16.
// Boundary to epilogue uses __syncthreads(): raw s_barrier is NOT a compiler
// memory fence, and other waves' tail STAGE DMAs land inside this wave's wlds.
__global__ __launch_bounds__(512, 2) void scores256(
    const u16* __restrict__ Qg, const u16* __restrict__ Kg,
    u16* __restrict__ Pg, const float* __restrict__ maskg) {
  constexpr int S = 4096, DK = 1024;
  __shared__ __align__(16) u16 lds[2][2][2][128 * 64];  // 128 KiB

  // T1 bijective XCD swizzle within each batch plane (256 tiles, 256%8==0)
  const int orig = blockIdx.x + (blockIdx.y << 4);
  const int logical = (orig & 7) * 32 + (orig >> 3);
  const int bm = logical >> 4, bn = logical & 15;
  const int z = blockIdx.z;

  const u16* A = Qg + (size_t)z * S * DK;
  const u16* Bt = Kg + (size_t)z * S * DK;
  const float* mask = maskg + (size_t)z * S * S;
  u16* Cb = Pg + (size_t)z * S * S;

  const int tid = threadIdx.x;
  const int wid = tid >> 6, lane = tid & 63;
  const int wr = wid >> 2, wc = wid & 3;      // 2x4 wave grid; wave tile 128x64
  const int fr = lane & 15, kq = lane >> 4;

  const int srow = (wid << 3) + (lane >> 3);  // staging row (+64 per issue)
  const int sslot = lane & 7;
  const int arow0 = bm * 256, brow0 = bn * 256;

  f32x4 acc[8][4];
#pragma unroll
  for (int i = 0; i < 8; i++)
#pragma unroll
    for (int j = 0; j < 4; j++) acc[i][j] = (f32x4)(0.f);
  bf16x8 a_[4][2], b_[4][2];

#define STAGE(bf, ab, hf, kt_) do {                                         \
    const u16* gp_ = (ab) ? Bt : A;                                         \
    const int rb_ = ((ab) ? brow0 : arow0) + (hf) * 128;                    \
    _Pragma("unroll")                                                       \
    for (int ii_ = 0; ii_ < 2; ii_++) {                                     \
      const int row_ = srow + ii_ * 64;                                     \
      const int c8_ = sslot ^ (row_ & 7);                                   \
      gload_lds16(gp_ + (size_t)(rb_ + row_) * DK + (kt_) + c8_ * 8,        \
                  &lds[bf][ab][hf][wid * 512 + ii_ * 4096]);                \
    }                                                                       \
  } while (0)

#define LDA_(bf, i_, kk_)                                                   \
  (*(const bf16x8*)&lds[bf][0][wr][((i_) * 16 + fr) * 64 +                  \
      ((((kk_) * 4 + kq) ^ (((i_) * 16 + fr) & 7)) * 8)])
#define LDB_(bf, j_, kk_)                                                   \
  (*(const bf16x8*)&lds[bf][1][wc >> 1][((wc & 1) * 64 + (j_) * 16 + fr) * 64 + \
      ((((kk_) * 4 + kq) ^ (((wc & 1) * 64 + (j_) * 16 + fr) & 7)) * 8)])

#define DSA(bf, ih) do {                                                    \
    _Pragma("unroll") for (int i_ = 0; i_ < 4; i_++)                        \
    _Pragma("unroll") for (int k_ = 0; k_ < 2; k_++)                        \
      a_[i_][k_] = LDA_(bf, (ih) + i_, k_);                                 \
  } while (0)
#define DSB(bf, jp) do {                                                    \
    _Pragma("unroll") for (int j_ = 0; j_ < 2; j_++)                        \
    _Pragma("unroll") for (int k_ = 0; k_ < 2; k_++)                        \
      b_[(jp) + j_][k_] = LDB_(bf, (jp) + j_, k_);                          \
  } while (0)
#define MF(ih, jp) do {                                                     \
    _Pragma("unroll") for (int i_ = 0; i_ < 4; i_++)                        \
    _Pragma("unroll") for (int j_ = 0; j_ < 2; j_++)                        \
    _Pragma("unroll") for (int k_ = 0; k_ < 2; k_++)                        \
      acc[(ih) + i_][(jp) + j_] = __builtin_amdgcn_mfma_f32_16x16x32_bf16(  \
          a_[i_][k_], b_[(jp) + j_][k_], acc[(ih) + i_][(jp) + j_], 0, 0, 0); \
  } while (0)
#define BAR() __builtin_amdgcn_s_barrier()
#define LGKM0() asm volatile("s_waitcnt lgkmcnt(0)" ::: "memory")
#define VMC4() asm volatile("s_waitcnt vmcnt(4)" ::: "memory")

  // prologue: tile0 full (A0,A1,B0,B1) + tile1 (B0,B1); drain to 4
  STAGE(0, 0, 0, 0); STAGE(0, 0, 1, 0); STAGE(0, 1, 0, 0); STAGE(0, 1, 1, 0);
  STAGE(1, 1, 0, 64); STAGE(1, 1, 1, 64);
  VMC4();
  BAR();

  constexpr int NIT = DK / 128;  // 8 iterations, 2 K-tiles each
#pragma unroll 1
  for (int t = 0; t < NIT; t++) {
    const int ktv = t * 128 + 64;
    const int kt2 = (t * 128 + 128 < DK) ? t * 128 + 128 : DK - 64;  // clamp tail
    const int kt3 = (t * 128 + 192 < DK) ? t * 128 + 192 : DK - 64;

    // --- tile u = 2t (buf0) ---
    DSA(0, 0); DSB(0, 0);
    STAGE(1, 0, 0, ktv);
    BAR(); LGKM0();
    __builtin_amdgcn_s_setprio(1); MF(0, 0); __builtin_amdgcn_s_setprio(0);
    BAR();
    DSB(0, 2);
    STAGE(1, 0, 1, ktv);
    BAR(); LGKM0();
    __builtin_amdgcn_s_setprio(1); MF(0, 2); __builtin_amdgcn_s_setprio(0);
    BAR();
    DSA(0, 4);
    STAGE(0, 1, 0, kt2);
    BAR(); LGKM0();
    __builtin_amdgcn_s_setprio(1); MF(4, 2); __builtin_amdgcn_s_setprio(0);
    BAR();
    STAGE(0, 1, 1, kt2);
    BAR(); LGKM0();
    __builtin_amdgcn_s_setprio(1); MF(4, 0); __builtin_amdgcn_s_setprio(0);
    VMC4();
    BAR();
    // --- tile v = 2t+1 (buf1) ---
    DSA(1, 0); DSB(1, 0);
    STAGE(0, 0, 0, kt2);
    BAR(); LGKM0();
    __builtin_amdgcn_s_setprio(1); MF(0, 0); __builtin_amdgcn_s_setprio(0);
    BAR();
    DSB(1, 2);
    STAGE(0, 0, 1, kt2);
    BAR(); LGKM0();
    __builtin_amdgcn_s_setprio(1); MF(0, 2); __builtin_amdgcn_s_setprio(0);
    BAR();
    DSA(1, 4);
    STAGE(1, 1, 0, kt3);
    BAR(); LGKM0();
    __builtin_amdgcn_s_setprio(1); MF(4, 2); __builtin_amdgcn_s_setprio(0);
    BAR();
    STAGE(1, 1, 1, kt3);
    BAR(); LGKM0();
    __builtin_amdgcn_s_setprio(1); MF(4, 0); __builtin_amdgcn_s_setprio(0);
    VMC4();
    BAR();
  }

  // ---- epilogue boundary: FULL fence + barrier (not raw s_barrier!) ----
  asm volatile("s_waitcnt vmcnt(0)" ::: "memory");
  __syncthreads();  // IR-level memory fence: no LDS op crosses; all waves' DMAs landed
  __builtin_amdgcn_sched_barrier(0);

  float* wlds = (float*)lds + wid * 4096;  // 64x64 f32 per wave (16 KiB)
  const int rr = lane >> 4, cc = lane & 15;
  const int rbase = bm * 256 + wr * 128;
  const int cbase = bn * 256 + wc * 64;

  // p_ MUST be a literal so acc[] indices are compile-time (rule #20).
#define EPIPASS(p_) do {                                                    \
    _Pragma("unroll") for (int ii = 0; ii < 4; ii++)                        \
    _Pragma("unroll") for (int j = 0; j < 4; j++)                           \
    _Pragma("unroll") for (int r = 0; r < 4; r++) {                         \
      const int row = ii * 16 + kq * 4 + r;                                 \
      const int col = (j * 16 + fr) ^ ((row & 7) << 2);                     \
      wlds[row * 64 + col] = acc[(p_) * 4 + ii][j][r];                      \
    }                                                                       \
    _Pragma("unroll 4") for (int rg = 0; rg < 16; rg++) {                   \
      const int row = rg * 4 + rr;                                          \
      const int colp = (cc * 4) ^ ((row & 7) << 2);                         \
      f32x4 s = *(f32x4*)&wlds[row * 64 + colp];                            \
      const int grow = rbase + (p_) * 64 + row;                             \
      const int gcol = cbase + cc * 4;                                      \
      const float4 m = *(const float4*)&mask[(size_t)grow * S + gcol];      \
      union { u16 h[4]; u64 q; } o;                                         \
      o.h[0] = f2bf(fsig(fsig(s[0]) * m.x));                                \
      o.h[1] = f2bf(fsig(fsig(s[1]) * m.y));                                \
      o.h[2] = f2bf(fsig(fsig(s[2]) * m.z));                                \
      o.h[3] = f2bf(fsig(fsig(s[3]) * m.w));                                \
      *(u64*)&Cb[(size_t)grow * S + gcol] = o.q;                            \
    }                                                                       \
  } while (0)

  EPIPASS(0);
  __builtin_amdgcn_sched_barrier(0);  // pin pass-0 reads before pass-1 writes
  EPIPASS(1);
#undef EPIPASS
#undef STAGE
#undef LDA_
#undef LDB_
#undef DSA
#undef DSB
#undef MF
#undef BAR
#undef LGKM0
#undef VMC4
}

extern "C" void kernel_launch(void* const* d_in, const int* in_sizes, int n_in,
                              void* d_out, int out_size, void* d_ws, size_t ws_size,
                              hipStream_t stream) {
  const int B = 2, S = 4096, D = 1024;
  const float* hid  = (const float*)d_in[0];
  const float* mask = (const float*)d_in[1];
  const float* Wq = (const float*)d_in[2];
  const float* bq = (const float*)d_in[3];
  const float* Wk = (const float*)d_in[4];
  const float* bk = (const float*)d_in[5];
  const float* Wv = (const float*)d_in[6];
  const float* bv = (const float*)d_in[7];

  const size_t MT = (size_t)B * S * D;  // 8388608
  u16* hbf = (u16*)d_ws;                // MT
  u16* wbf = hbf + MT;                  // 3*D*D
  u16* Qb  = wbf + 3 * (size_t)D * D;   // MT  (Q,K contiguous; z=2 writes VTb)
  u16* Kb  = Qb + MT;
  u16* Vb  = Kb + MT;                   // (unused now; kept for layout stability)
  u16* VTb = Vb + MT;                   // MT
  u16* Pb  = VTb + MT;                  // B*S*S

  // 1. converts
  cvt_bf16<<<2048, 256, 0, stream>>>((const float4*)hid, hbf, (int)(MT / 4));
  cvt_w3<<<dim3(512, 1, 3), 256, 0, stream>>>(
      (const float4*)Wq, (const float4*)Wk, (const float4*)Wv, wbf, D * D / 4);

  // 2. fused QKV projection; V (z==2) is written transposed to VTb directly
  gemm_bt<0><<<dim3(B * S / 128, D / 128, 3), 256, 0, stream>>>(
      hbf, wbf, Qb, nullptr, VTb, bq, bk, bv, B * S, D, D);

  // 3. scores (256^2 8-phase + fenced vectorized epilogue), both batches
  scores256<<<dim3(S / 256, S / 256, B), 512, 0, stream>>>(Qb, Kb, Pb, mask);

  // 4. P*V
  gemm_bt<2><<<dim3(S / 128, D / 128, B), 256, 0, stream>>>(
      Pb, VTb, nullptr, (float*)d_out, nullptr, nullptr, nullptr, nullptr, S, D, S);
}

// Round 12
// 244.990 us; speedup vs baseline: 1.1141x; 1.0065x over previous
//
#include <hip/hip_runtime.h>
#include <hip/hip_bf16.h>

typedef unsigned short u16;
typedef unsigned long long u64;
typedef __attribute__((ext_vector_type(8))) __bf16 bf16x8;
typedef __attribute__((ext_vector_type(4))) float f32x4;

#define DEV static __device__ __forceinline__

DEV u16 f2bf(float f) {
  union { float f; unsigned u; } c; c.f = f;
  unsigned r = c.u + 0x7fffu + ((c.u >> 16) & 1u);
  return (u16)(r >> 16);
}
DEV float fsig(float x) { return 1.f / (1.f + __expf(-x)); }

DEV void gload_lds16(const void* g, void* l) {
  __builtin_amdgcn_global_load_lds(
      (const __attribute__((address_space(1))) void*)g,
      (__attribute__((address_space(3))) void*)l, 16, 0, 0);
}

// fp32 -> bf16 elementwise (RNE), float4-vectorized
__global__ void cvt_bf16(const float4* __restrict__ src, u16* __restrict__ dst, int n4) {
  int i = blockIdx.x * blockDim.x + threadIdx.x;
  int stride = gridDim.x * blockDim.x;
  for (; i < n4; i += stride) {
    float4 v = src[i];
    union { u16 s[4]; u64 q; } o;
    o.s[0] = f2bf(v.x); o.s[1] = f2bf(v.y); o.s[2] = f2bf(v.z); o.s[3] = f2bf(v.w);
    *(u64*)&dst[(size_t)i * 4] = o.q;
  }
}

__global__ void cvt_w3(const float4* __restrict__ s0, const float4* __restrict__ s1,
                       const float4* __restrict__ s2, u16* __restrict__ dst, int n4) {
  const float4* src = blockIdx.z == 0 ? s0 : (blockIdx.z == 1 ? s1 : s2);
  u16* d = dst + (size_t)blockIdx.z * n4 * 4;
  int i = blockIdx.x * blockDim.x + threadIdx.x;
  int stride = gridDim.x * blockDim.x;
  for (; i < n4; i += stride) {
    float4 v = src[i];
    union { u16 s[4]; u64 q; } o;
    o.s[0] = f2bf(v.x); o.s[1] = f2bf(v.y); o.s[2] = f2bf(v.z); o.s[3] = f2bf(v.w);
    *(u64*)&d[(size_t)i * 4] = o.q;
  }
}

// ---------- 128^2 m97-structure GEMM (QKV projection) ----------
// z=0: Q (scaled 1/32) -> Cb; z=1: K -> Cb;
// z=2: V -> written TRANSPOSED to VTb (per batch) via in-LDS transpose.
template <int EPI>
__global__ __launch_bounds__(256, 2) void gemm_bt(
    const u16* __restrict__ A, const u16* __restrict__ Bt,
    u16* __restrict__ Cb, float* __restrict__ Cf, u16* __restrict__ VTb,
    const float* __restrict__ bias0, const float* __restrict__ bias1,
    const float* __restrict__ bias2,
    int M, int N, int K) {
  __shared__ __align__(16) u16 smem[2 * 128 * 64];  // As | Bs (contiguous)
  u16* As = smem;
  u16* Bs = smem + 128 * 64;

  const int bm = blockIdx.x, bn = blockIdx.y, z = blockIdx.z;
  if (EPI == 0) {
    Bt += (size_t)z * N * K;
  } else {
    A += (size_t)z * M * K;
    Bt += (size_t)z * N * K;
  }
  const size_t cofs = (size_t)z * M * N;
  const float* bias = (EPI == 0) ? (z == 0 ? bias0 : (z == 1 ? bias1 : bias2)) : nullptr;
  const float scale = (EPI == 0 && z == 0) ? 0.03125f : 1.0f;

  const int tid = threadIdx.x;
  const int wid = tid >> 6, lane = tid & 63;
  const int wr = wid >> 1, wc = wid & 1;
  const int l3 = lane >> 3, sl = lane & 7;
  const int srcslot = sl ^ l3;

  const u16* Ag = A + (size_t)(bm * 128 + wid * 32 + l3) * K + srcslot * 8;
  const u16* Bg = Bt + (size_t)(bn * 128 + wid * 32 + l3) * K + srcslot * 8;
  u16* AsW = &As[wid * 32 * 64];
  u16* BsW = &Bs[wid * 32 * 64];

  f32x4 acc[4][4];
#pragma unroll
  for (int i = 0; i < 4; i++)
#pragma unroll
    for (int j = 0; j < 4; j++) acc[i][j] = (f32x4)(0.f);

  const int fr = lane & 15, kq = lane >> 4;

  for (int kt = 0; kt < K; kt += 64) {
#pragma unroll
    for (int i = 0; i < 4; i++) {
      gload_lds16(Ag + kt + i * 8 * K, AsW + i * 8 * 64);
      gload_lds16(Bg + kt + i * 8 * K, BsW + i * 8 * 64);
    }
    __syncthreads();
#pragma unroll
    for (int ks = 0; ks < 2; ks++) {
      bf16x8 af[4], bfr[4];
#pragma unroll
      for (int i = 0; i < 4; i++) {
        const int ra = wr * 64 + i * 16 + fr;
        af[i] = *(const bf16x8*)&As[ra * 64 + (((ks * 4 + kq) ^ (ra & 7)) * 8)];
        const int rb = wc * 64 + i * 16 + fr;
        bfr[i] = *(const bf16x8*)&Bs[rb * 64 + (((ks * 4 + kq) ^ (rb & 7)) * 8)];
      }
#pragma unroll
      for (int i = 0; i < 4; i++)
#pragma unroll
        for (int j = 0; j < 4; j++)
          acc[i][j] = __builtin_amdgcn_mfma_f32_16x16x32_bf16(af[i], bfr[j], acc[i][j], 0, 0, 0);
    }
    __syncthreads();
  }
  // after the final __syncthreads() above, all waves are done reading smem.

  const int rbase = bm * 128 + wr * 64;
  const int cbase = bn * 128 + wc * 64;

  if (EPI == 0 && z == 2) {
    // ---- V: write transposed via per-wave 64x64 bf16 LDS transpose ----
    u16* tl = smem + wid * 4096;
#pragma unroll
    for (int i = 0; i < 4; i++)
#pragma unroll
      for (int j = 0; j < 4; j++) {
        const int dl = j * 16 + fr;          // transposed row (d-local)
        const int slot = i * 4 + kq;         // 4 u16 along s-local
        union { u16 h[4]; u64 q; } o;
#pragma unroll
        for (int r = 0; r < 4; r++) o.h[r] = f2bf(acc[i][j][r] + bias[cbase + dl]);
        *(u64*)&tl[dl * 64 + ((slot ^ (dl & 15)) * 4)] = o.q;
      }
    const int batch = bm >> 5;               // bm*128 / 4096
    u16* VTw = VTb + (size_t)batch * 4096 * 1024;
    const int d0 = cbase;
    const int s0 = rbase - batch * 4096;
    const int rl = lane >> 4, sslot2 = lane & 15;
#pragma unroll
    for (int rb = 0; rb < 16; rb++) {
      const int dl = rb * 4 + rl;
      const u64 q = *(const u64*)&tl[dl * 64 + ((sslot2 ^ (dl & 15)) * 4)];
      *(u64*)&VTw[(size_t)(d0 + dl) * 4096 + s0 + sslot2 * 4] = q;
    }
  } else {
#pragma unroll
    for (int i = 0; i < 4; i++)
#pragma unroll
      for (int j = 0; j < 4; j++) {
        const int col = cbase + j * 16 + fr;
#pragma unroll
        for (int r = 0; r < 4; r++) {
          const int row = rbase + i * 16 + kq * 4 + r;
          float v = acc[i][j][r];
          if (EPI == 0) {
            v = (v + bias[col]) * scale;
            Cb[cofs + (size_t)row * N + col] = f2bf(v);
          } else {
            Cf[cofs + (size_t)row * N + col] = v;
          }
        }
      }
  }
}

// ---------- scores: 256x256-tile, BK=64, 8-wave, 8-phase counted-vmcnt ----------
// P = sigmoid(sigmoid(Q*K^T)*mask), Q pre-scaled by 1/32. z = batch.
__global__ __launch_bounds__(512, 2) void scores256(
    const u16* __restrict__ Qg, const u16* __restrict__ Kg,
    u16* __restrict__ Pg, const float* __restrict__ maskg) {
  constexpr int S = 4096, DK = 1024;
  __shared__ __align__(16) u16 lds[2][2][2][128 * 64];  // 128 KiB

  const int orig = blockIdx.x + (blockIdx.y << 4);
  const int logical = (orig & 7) * 32 + (orig >> 3);
  const int bm = logical >> 4, bn = logical & 15;
  const int z = blockIdx.z;

  const u16* A = Qg + (size_t)z * S * DK;
  const u16* Bt = Kg + (size_t)z * S * DK;
  const float* mask = maskg + (size_t)z * S * S;
  u16* Cb = Pg + (size_t)z * S * S;

  const int tid = threadIdx.x;
  const int wid = tid >> 6, lane = tid & 63;
  const int wr = wid >> 2, wc = wid & 3;
  const int fr = lane & 15, kq = lane >> 4;

  const int srow = (wid << 3) + (lane >> 3);
  const int sslot = lane & 7;
  const int arow0 = bm * 256, brow0 = bn * 256;

  f32x4 acc[8][4];
#pragma unroll
  for (int i = 0; i < 8; i++)
#pragma unroll
    for (int j = 0; j < 4; j++) acc[i][j] = (f32x4)(0.f);
  bf16x8 a_[4][2], b_[4][2];

#define STAGE(bf, ab, hf, kt_) do {                                         \
    const u16* gp_ = (ab) ? Bt : A;                                         \
    const int rb_ = ((ab) ? brow0 : arow0) + (hf) * 128;                    \
    _Pragma("unroll")                                                       \
    for (int ii_ = 0; ii_ < 2; ii_++) {                                     \
      const int row_ = srow + ii_ * 64;                                     \
      const int c8_ = sslot ^ (row_ & 7);                                   \
      gload_lds16(gp_ + (size_t)(rb_ + row_) * DK + (kt_) + c8_ * 8,        \
                  &lds[bf][ab][hf][wid * 512 + ii_ * 4096]);                \
    }                                                                       \
  } while (0)

#define LDA_(bf, i_, kk_)                                                   \
  (*(const bf16x8*)&lds[bf][0][wr][((i_) * 16 + fr) * 64 +                  \
      ((((kk_) * 4 + kq) ^ (((i_) * 16 + fr) & 7)) * 8)])
#define LDB_(bf, j_, kk_)                                                   \
  (*(const bf16x8*)&lds[bf][1][wc >> 1][((wc & 1) * 64 + (j_) * 16 + fr) * 64 + \
      ((((kk_) * 4 + kq) ^ (((wc & 1) * 64 + (j_) * 16 + fr) & 7)) * 8)])

#define DSA(bf, ih) do {                                                    \
    _Pragma("unroll") for (int i_ = 0; i_ < 4; i_++)                        \
    _Pragma("unroll") for (int k_ = 0; k_ < 2; k_++)                        \
      a_[i_][k_] = LDA_(bf, (ih) + i_, k_);                                 \
  } while (0)
#define DSB(bf, jp) do {                                                    \
    _Pragma("unroll") for (int j_ = 0; j_ < 2; j_++)                        \
    _Pragma("unroll") for (int k_ = 0; k_ < 2; k_++)                        \
      b_[(jp) + j_][k_] = LDB_(bf, (jp) + j_, k_);                          \
  } while (0)
#define MF(ih, jp) do {                                                     \
    _Pragma("unroll") for (int i_ = 0; i_ < 4; i_++)                        \
    _Pragma("unroll") for (int j_ = 0; j_ < 2; j_++)                        \
    _Pragma("unroll") for (int k_ = 0; k_ < 2; k_++)                        \
      acc[(ih) + i_][(jp) + j_] = __builtin_amdgcn_mfma_f32_16x16x32_bf16(  \
          a_[i_][k_], b_[(jp) + j_][k_], acc[(ih) + i_][(jp) + j_], 0, 0, 0); \
  } while (0)
#define BAR() __builtin_amdgcn_s_barrier()
#define LGKM0() asm volatile("s_waitcnt lgkmcnt(0)" ::: "memory")
#define VMC4() asm volatile("s_waitcnt vmcnt(4)" ::: "memory")

  STAGE(0, 0, 0, 0); STAGE(0, 0, 1, 0); STAGE(0, 1, 0, 0); STAGE(0, 1, 1, 0);
  STAGE(1, 1, 0, 64); STAGE(1, 1, 1, 64);
  VMC4();
  BAR();

  constexpr int NIT = DK / 128;
#pragma unroll 1
  for (int t = 0; t < NIT; t++) {
    const int ktv = t * 128 + 64;
    const int kt2 = (t * 128 + 128 < DK) ? t * 128 + 128 : DK - 64;
    const int kt3 = (t * 128 + 192 < DK) ? t * 128 + 192 : DK - 64;

    DSA(0, 0); DSB(0, 0);
    STAGE(1, 0, 0, ktv);
    BAR(); LGKM0();
    __builtin_amdgcn_s_setprio(1); MF(0, 0); __builtin_amdgcn_s_setprio(0);
    BAR();
    DSB(0, 2);
    STAGE(1, 0, 1, ktv);
    BAR(); LGKM0();
    __builtin_amdgcn_s_setprio(1); MF(0, 2); __builtin_amdgcn_s_setprio(0);
    BAR();
    DSA(0, 4);
    STAGE(0, 1, 0, kt2);
    BAR(); LGKM0();
    __builtin_amdgcn_s_setprio(1); MF(4, 2); __builtin_amdgcn_s_setprio(0);
    BAR();
    STAGE(0, 1, 1, kt2);
    BAR(); LGKM0();
    __builtin_amdgcn_s_setprio(1); MF(4, 0); __builtin_amdgcn_s_setprio(0);
    VMC4();
    BAR();
    DSA(1, 0); DSB(1, 0);
    STAGE(0, 0, 0, kt2);
    BAR(); LGKM0();
    __builtin_amdgcn_s_setprio(1); MF(0, 0); __builtin_amdgcn_s_setprio(0);
    BAR();
    DSB(1, 2);
    STAGE(0, 0, 1, kt2);
    BAR(); LGKM0();
    __builtin_amdgcn_s_setprio(1); MF(0, 2); __builtin_amdgcn_s_setprio(0);
    BAR();
    DSA(1, 4);
    STAGE(1, 1, 0, kt3);
    BAR(); LGKM0();
    __builtin_amdgcn_s_setprio(1); MF(4, 2); __builtin_amdgcn_s_setprio(0);
    BAR();
    STAGE(1, 1, 1, kt3);
    BAR(); LGKM0();
    __builtin_amdgcn_s_setprio(1); MF(4, 0); __builtin_amdgcn_s_setprio(0);
    VMC4();
    BAR();
  }

  asm volatile("s_waitcnt vmcnt(0)" ::: "memory");
  __syncthreads();
  __builtin_amdgcn_sched_barrier(0);

  float* wlds = (float*)lds + wid * 4096;
  const int rr = lane >> 4, cc = lane & 15;
  const int rbase = bm * 256 + wr * 128;
  const int cbase = bn * 256 + wc * 64;

#define EPIPASS(p_) do {                                                    \
    _Pragma("unroll") for (int ii = 0; ii < 4; ii++)                        \
    _Pragma("unroll") for (int j = 0; j < 4; j++)                           \
    _Pragma("unroll") for (int r = 0; r < 4; r++) {                         \
      const int row = ii * 16 + kq * 4 + r;                                 \
      const int col = (j * 16 + fr) ^ ((row & 7) << 2);                     \
      wlds[row * 64 + col] = acc[(p_) * 4 + ii][j][r];                      \
    }                                                                       \
    _Pragma("unroll 4") for (int rg = 0; rg < 16; rg++) {                   \
      const int row = rg * 4 + rr;                                          \
      const int colp = (cc * 4) ^ ((row & 7) << 2);                         \
      f32x4 s = *(f32x4*)&wlds[row * 64 + colp];                            \
      const int grow = rbase + (p_) * 64 + row;                             \
      const int gcol = cbase + cc * 4;                                      \
      const float4 m = *(const float4*)&mask[(size_t)grow * S + gcol];      \
      union { u16 h[4]; u64 q; } o;                                         \
      o.h[0] = f2bf(fsig(fsig(s[0]) * m.x));                                \
      o.h[1] = f2bf(fsig(fsig(s[1]) * m.y));                                \
      o.h[2] = f2bf(fsig(fsig(s[2]) * m.z));                                \
      o.h[3] = f2bf(fsig(fsig(s[3]) * m.w));                                \
      *(u64*)&Cb[(size_t)grow * S + gcol] = o.q;                            \
    }                                                                       \
  } while (0)

  EPIPASS(0);
  __builtin_amdgcn_sched_barrier(0);
  EPIPASS(1);
#undef EPIPASS
#undef STAGE
#undef LDA_
#undef LDB_
#undef DSA
#undef DSB
#undef MF
#undef BAR
#undef LGKM0
#undef VMC4
}

// ---------- PV: 128x256-tile scores-skeleton clone, 8-wave, counted-vmcnt ----------
// O[b][s][d] = P[b][s][:] * VT[b][d][:] (both K-major, K=4096). Batches merged in M.
// Grid (64,4) = 256 blocks. Waves 2x4, wave tile 64x64, acc[4][4].
// Stage invariant (from scores): a buffer is staged only in a phase strictly
// after its last-read phase. Gates: vmcnt(2) at P2/P4 (in-flight peaks at 8).
__global__ __launch_bounds__(512, 2) void pv128x256(
    const u16* __restrict__ Pg, const u16* __restrict__ VTg,
    float* __restrict__ Og) {
  constexpr int S = 4096, DN = 1024, DK = 4096;
  __shared__ __align__(16) u16 lds[2][3][128 * 64];  // [buf][0=A,1=B0,2=B1], 96 KiB

  const int orig = blockIdx.x + (blockIdx.y << 6);    // 256 blocks, 256%8==0
  const int logical = (orig & 7) * 32 + (orig >> 3);  // bijective XCD chunking
  const int bm = logical >> 2, bn = logical & 3;      // bm-major: P-panel reuse

  const int batch = bm >> 5;                          // 64 tiles, 32 per batch
  const u16* A = Pg + (size_t)batch * S * S;
  const u16* Bt = VTg + (size_t)batch * DN * S;
  float* C = Og + (size_t)batch * S * DN;
  const int arow0 = (bm & 31) * 128;
  const int brow0 = bn * 256;

  const int tid = threadIdx.x;
  const int wid = tid >> 6, lane = tid & 63;
  const int wr = wid >> 2, wc = wid & 3;              // 2 row-waves x 4 col-waves
  const int fr = lane & 15, kq = lane >> 4;
  const int srow = (wid << 3) + (lane >> 3);
  const int sslot = lane & 7;

  f32x4 acc[4][4];
#pragma unroll
  for (int i = 0; i < 4; i++)
#pragma unroll
    for (int j = 0; j < 4; j++) acc[i][j] = (f32x4)(0.f);
  bf16x8 a_[4][2], b_[4][2];

#define PSTA(bf, kt_) do {                                                  \
    _Pragma("unroll")                                                       \
    for (int ii_ = 0; ii_ < 2; ii_++) {                                     \
      const int row_ = srow + ii_ * 64;                                     \
      const int c8_ = sslot ^ (row_ & 7);                                   \
      gload_lds16(A + (size_t)(arow0 + row_) * DK + (kt_) + c8_ * 8,        \
                  &lds[bf][0][wid * 512 + ii_ * 4096]);                     \
    }                                                                       \
  } while (0)
#define PSTB(bf, hf, kt_) do {                                              \
    _Pragma("unroll")                                                       \
    for (int ii_ = 0; ii_ < 2; ii_++) {                                     \
      const int row_ = srow + ii_ * 64;                                     \
      const int c8_ = sslot ^ (row_ & 7);                                   \
      gload_lds16(Bt + (size_t)(brow0 + (hf) * 128 + row_) * DK + (kt_) + c8_ * 8, \
                  &lds[bf][1 + (hf)][wid * 512 + ii_ * 4096]);              \
    }                                                                       \
  } while (0)
#define PDSA(bf) do {                                                       \
    _Pragma("unroll") for (int i_ = 0; i_ < 4; i_++)                        \
    _Pragma("unroll") for (int k_ = 0; k_ < 2; k_++) {                      \
      const int ra_ = wr * 64 + i_ * 16 + fr;                               \
      a_[i_][k_] = *(const bf16x8*)&lds[bf][0][ra_ * 64 +                   \
          (((k_ * 4 + kq) ^ (ra_ & 7)) * 8)];                               \
    }                                                                       \
  } while (0)
#define PDSB(bf, jp) do {                                                   \
    _Pragma("unroll") for (int j_ = 0; j_ < 2; j_++)                        \
    _Pragma("unroll") for (int k_ = 0; k_ < 2; k_++) {                      \
      const int rb_ = (wc & 1) * 64 + ((jp) + j_) * 16 + fr;                \
      b_[(jp) + j_][k_] = *(const bf16x8*)&lds[bf][1 + (wc >> 1)][rb_ * 64 + \
          (((k_ * 4 + kq) ^ (rb_ & 7)) * 8)];                               \
    }                                                                       \
  } while (0)
#define PMF(jp) do {                                                        \
    _Pragma("unroll") for (int i_ = 0; i_ < 4; i_++)                        \
    _Pragma("unroll") for (int j_ = 0; j_ < 2; j_++)                        \
    _Pragma("unroll") for (int k_ = 0; k_ < 2; k_++)                        \
      acc[i_][(jp) + j_] = __builtin_amdgcn_mfma_f32_16x16x32_bf16(         \
          a_[i_][k_], b_[(jp) + j_][k_], acc[i_][(jp) + j_], 0, 0, 0);      \
  } while (0)
#define BAR() __builtin_amdgcn_s_barrier()
#define LGKM0() asm volatile("s_waitcnt lgkmcnt(0)" ::: "memory")
#define VMC2() asm volatile("s_waitcnt vmcnt(2)" ::: "memory")
#define PRIO1() __builtin_amdgcn_s_setprio(1)
#define PRIO0() __builtin_amdgcn_s_setprio(0)

  // prologue: A(0)[2] B(0)h0[2] B(0)h1[2], A(1)[2]; drain to 2 (A(1) in flight)
  PSTA(0, 0); PSTB(0, 0, 0); PSTB(0, 1, 0);
  PSTA(1, 64);
  VMC2();
  BAR();

  constexpr int NP = DK / 128;  // 32 iterations; tiles u=2t (buf0), v=2t+1 (buf1)
#pragma unroll 1
  for (int t = 0; t < NP; t++) {
    const int ktv = t * 128 + 64;
    const int ku2 = (t * 128 + 128 < DK) ? t * 128 + 128 : DK - 64;  // clamp tail
    const int kv2 = (t * 128 + 192 < DK) ? t * 128 + 192 : DK - 64;

    // P1: tile u cols j0-1; stage B(v)h0 -> buf1-B (last read prev-P4)
    PDSA(0); PDSB(0, 0); PSTB(1, 0, ktv);
    BAR(); LGKM0(); PRIO1(); PMF(0); PRIO0(); BAR();
    // P2: tile u cols j2-3; stage B(v)h1 + A(u+2) -> buf0-A (last read P1)
    PDSB(0, 2); PSTB(1, 1, ktv); PSTA(0, ku2);
    BAR(); LGKM0(); PRIO1(); PMF(2); PRIO0();
    VMC2();  // in-flight {A(v)2,Bv_h0 2,Bv_h1 2,A(u+2)2}=8 -> drain 6, leave A(u+2)
    BAR();
    // P3: tile v cols j0-1; stage B(u+2)h0 -> buf0-B (last read P2)
    PDSA(1); PDSB(1, 0); PSTB(0, 0, ku2);
    BAR(); LGKM0(); PRIO1(); PMF(0); PRIO0(); BAR();
    // P4: tile v cols j2-3; stage B(u+2)h1 + A(v+2) -> buf1-A (last read P3)
    PDSB(1, 2); PSTB(0, 1, ku2); PSTA(1, kv2);
    BAR(); LGKM0(); PRIO1(); PMF(2); PRIO0();
    VMC2();  // in-flight {A(u+2)2,Bu2_h0 2,Bu2_h1 2,A(v+2)2}=8 -> leave A(v+2)
    BAR();
  }

  asm volatile("s_waitcnt vmcnt(0)" ::: "memory");

  // epilogue: direct coalesced fp32 stores
  const int rbase0 = arow0 + wr * 64;
  const int cbase = bn * 256 + wc * 64;
#pragma unroll
  for (int i = 0; i < 4; i++)
#pragma unroll
    for (int j = 0; j < 4; j++) {
      const int col = cbase + j * 16 + fr;
#pragma unroll
      for (int r = 0; r < 4; r++) {
        const int row = rbase0 + i * 16 + kq * 4 + r;
        C[(size_t)row * DN + col] = acc[i][j][r];
      }
    }
#undef PSTA
#undef PSTB
#undef PDSA
#undef PDSB
#undef PMF
#undef BAR
#undef LGKM0
#undef VMC2
#undef PRIO1
#undef PRIO0
}

extern "C" void kernel_launch(void* const* d_in, const int* in_sizes, int n_in,
                              void* d_out, int out_size, void* d_ws, size_t ws_size,
                              hipStream_t stream) {
  const int B = 2, S = 4096, D = 1024;
  const float* hid  = (const float*)d_in[0];
  const float* mask = (const float*)d_in[1];
  const float* Wq = (const float*)d_in[2];
  const float* bq = (const float*)d_in[3];
  const float* Wk = (const float*)d_in[4];
  const float* bk = (const float*)d_in[5];
  const float* Wv = (const float*)d_in[6];
  const float* bv = (const float*)d_in[7];

  const size_t MT = (size_t)B * S * D;  // 8388608
  u16* hbf = (u16*)d_ws;                // MT
  u16* wbf = hbf + MT;                  // 3*D*D
  u16* Qb  = wbf + 3 * (size_t)D * D;   // MT  (Q,K contiguous; z=2 writes VTb)
  u16* Kb  = Qb + MT;
  u16* Vb  = Kb + MT;                   // (unused; kept for layout stability)
  u16* VTb = Vb + MT;                   // MT
  u16* Pb  = VTb + MT;                  // B*S*S

  // 1. converts
  cvt_bf16<<<2048, 256, 0, stream>>>((const float4*)hid, hbf, (int)(MT / 4));
  cvt_w3<<<dim3(512, 1, 3), 256, 0, stream>>>(
      (const float4*)Wq, (const float4*)Wk, (const float4*)Wv, wbf, D * D / 4);

  // 2. fused QKV projection; V (z==2) is written transposed to VTb directly
  gemm_bt<0><<<dim3(B * S / 128, D / 128, 3), 256, 0, stream>>>(
      hbf, wbf, Qb, nullptr, VTb, bq, bk, bv, B * S, D, D);

  // 3. scores (256^2 8-phase + fenced vectorized epilogue), both batches
  scores256<<<dim3(S / 256, S / 256, B), 512, 0, stream>>>(Qb, Kb, Pb, mask);

  // 4. P*V (128x256 scores-skeleton, batches merged in M)
  pv128x256<<<dim3(64, 4), 512, 0, stream>>>(Pb, VTb, (float*)d_out);
}